// Round 24
// baseline (2806.289 us; speedup 1.0000x reference)
//
#include <hip/hip_runtime.h>

typedef _Float16 f16;
typedef _Float16 f16x8 __attribute__((ext_vector_type(8)));
typedef float f32x4 __attribute__((ext_vector_type(4)));

__device__ __forceinline__ f16x8 cvt8(f32x4 lo, f32x4 hi) {
    f16x8 h;
    h[0] = (f16)lo[0]; h[1] = (f16)lo[1]; h[2] = (f16)lo[2]; h[3] = (f16)lo[3];
    h[4] = (f16)hi[0]; h[5] = (f16)hi[1]; h[6] = (f16)hi[2]; h[7] = (f16)hi[3];
    return h;
}

__global__ __launch_bounds__(256)
void cvt_f32_f16(const float* __restrict__ in, f16* __restrict__ out, long long n) {
    long long i = ((long long)blockIdx.x * 256 + threadIdx.x) * 8;
    const long long stride = (long long)gridDim.x * 256 * 8;
    for (; i < n; i += stride) {
        f32x4 a = *(const f32x4*)(in + i);
        f32x4 b = *(const f32x4*)(in + i + 4);
        *(f16x8*)(out + i) = cvt8(a, b);
    }
}

// Interleave Wg/Wu rows 16-wise into Wgu [2M, HD] f16 (r22, verified):
//   Wgu row R: (R&31)<16 -> Wg row (R>>5)*16+(R&15); else Wu same.
__global__ __launch_bounds__(256)
void cvt_interleave_f32_f16(const float* __restrict__ Wg,
                            const float* __restrict__ Wu,
                            f16* __restrict__ out, long long total) {
    long long i = ((long long)blockIdx.x * 256 + threadIdx.x) * 8;
    const long long stride = (long long)gridDim.x * 256 * 8;
    for (; i < total; i += stride) {
        const long long row = i >> 12;           // HD = 4096
        const int col = (int)(i & 4095);
        const long long srow = ((row >> 5) << 4) | (row & 15);
        const float* src = ((row & 16) ? Wu : Wg) + srow * 4096 + col;
        *(f16x8*)(out + i) = cvt8(*(const f32x4*)src, *(const f32x4*)(src + 4));
    }
}

__global__ void fill_sentinel_f32(float* __restrict__ out, long long n) {
    long long i = (long long)blockIdx.x * blockDim.x + threadIdx.x;
    long long stride = (long long)gridDim.x * blockDim.x;
    for (; i < n; i += stride) out[i] = 1.0f;
}

// Async global->LDS, 16B/lane. Pass the WAVE-UNIFORM LDS base; HW adds lane*16.
__device__ __forceinline__ void gload_lds16(const f16* g, f16* l) {
    __builtin_amdgcn_global_load_lds(
        (const __attribute__((address_space(1))) unsigned int*)(unsigned long long)g,
        (__attribute__((address_space(3))) unsigned int*)(unsigned int)(unsigned long long)l,
        16, 0, 0);
}

// phase helpers (r23's PHASE_TAIL macro, de-macro'd for hipcc pragma rules)
__device__ __forceinline__ void phase_pre() {
    __builtin_amdgcn_s_barrier();
    asm volatile("s_waitcnt lgkmcnt(0)" ::: "memory");
    __builtin_amdgcn_sched_barrier(0);   // rule #18: pin MFMA below the wait
    __builtin_amdgcn_s_setprio(1);
}
__device__ __forceinline__ void phase_post() {
    __builtin_amdgcn_s_setprio(0);
    __builtin_amdgcn_s_barrier();
}

// ====================== 8-phase single-B NT GEMM (m201 port) =================
// BM=BN=256, BK=64 (2 x 32-K subtiles ks0/ks1), 512 thr (8 waves 2Mx4N),
// wave 128x64, acc = 32 f32x4. LDS = 2 dbuf x 2 ks x [256][32] x {A,B} = 128KB.
// Per K-tile t (buf c=t&1), FOUR double-barrier phases, 16 MFMA each:
//   p0: read aF(ks0,mi0-3)+bF0(ks0)  | stage A[c^1][ks1] (tile t+1)
//   p1: read aF(ks0,mi4-7)           | stage B[c][ks0]  (tile t+2)
//   p2: read aF(ks1,mi0-3)+bF1(ks1)  | stage A[c][ks0]  (tile t+2)
//   p3: read aF(ks1,mi4-7)           | stage B[c][ks1]  (tile t+2)
//   each phase: reads, gloads, phase_pre() {barrier, lgkmcnt(0),
//   sched_barrier, setprio(1)}, 16 MFMA, phase_post() {setprio(0), barrier}.
// Race-freedom: a region is staged 1-2 phases AFTER its last-read phase's
//   trailing barrier (B[ks0] last read p0 -> staged p1; A[ks0] p1 -> p2;
//   B[ks1] p2 -> p3; A[ks1] p3 -> next tile's p0 into other buf). Register
//   copies (bF0/bF1) survive overwrites. ds_reads retire at each phase's
//   lgkmcnt(0), before the trailing barrier any later stage follows.
// Counted vmcnt (T4): end of tile t waits vmcnt(6) = stages issued after
//   tile (t+1)'s last region (t's p1+p2+p3 = 6 gloads) -> t+1 fully landed,
//   6 loads stay in flight. Tail tiles drain with vmcnt(0). Prologue: 14
//   gloads (t0 full 8 + t1's A[ks0],B[ks0],B[ks1]), vmcnt(6) retires t0's 8.
// Pointer invariant: each stageA/stageB advances its pointers +32 k; stage
//   events for A (and for B) are issued in strictly increasing k order.
// Swizzle (0 conflicts, r8-r22): row 64B = 4x16B blks; LDS[r][blk] holds
//   global blk (blk - r/2)&3; read blk (hi + r/2)&3. gload dest LINEAR.
// MFMA 16x16x32 f16; C/D col=lane&15, row=(lane>>4)*4+j (verified).
// EPI=0 (down): f32 out. EPI=3 (gate+up, interleaved Wgu): ni even/odd =
//   gate/up same col; epilogue silu(g)*u in-register -> f16 H (r22, verified).
template<int EPI>
__global__ __launch_bounds__(512, 2)
void mlp_gemm8p(const f16* __restrict__ A, const f16* __restrict__ B0,
                void* __restrict__ Cv, int K, int ldc,
                int nRow, int nCol, int RG) {
    __shared__ __align__(16) f16 smA[2][2][256 * 32];   // [buf][ks] : 64 KB
    __shared__ __align__(16) f16 smB[2][2][256 * 32];   // 64 KB

    // ---- block remap: supergroups of RG row-blocks, col-outer within ----
    const int lin   = blockIdx.x;
    const int perSg = RG * nCol;
    const int sg    = lin / perSg;
    const int rem   = lin - sg * perSg;
    int rgIn = nRow - sg * RG; if (rgIn > RG) rgIn = RG;
    const int colB = rem / rgIn;
    const int rowB = sg * RG + (rem - colB * rgIn);

    const long long blockRow = (long long)rowB * 256;
    const long long blockCol = (long long)colB * 256;

    const int tid  = threadIdx.x;
    const int w    = tid >> 6;      // 0..7
    const int lane = tid & 63;
    const int waveM = w >> 2;       // 0..1 -> 128 rows
    const int waveN = w & 3;        // 0..3 -> 64 B-rows

    // ---- staging: thread covers 16B chunk (dr=tid>>2, blk=tid&3);
    // pre-rotated global source block gblk = (blk - dr/2)&3 (m173 pattern).
    const int dr   = tid >> 2;
    const int dblk = tid & 3;
    const int gblk = (dblk - (dr >> 1)) & 3;
    const f16* gA0 = A  + (blockRow + dr) * (long long)K + gblk * 8;  // rows 0-127
    const f16* gA1 = gA0 + 128 * (long long)K;                        // rows 128-255
    const f16* gB0 = B0 + (blockCol + dr) * (long long)K + gblk * 8;
    const f16* gB1 = gB0 + 128 * (long long)K;
    const int wbase = w * 512;      // wave-uniform LDS base within [256][32]

    auto stageA = [&](int b, int ks) {   // 2 gloads; k advances +32
        gload_lds16(gA0, &smA[b][ks][wbase]);        gA0 += 32;
        gload_lds16(gA1, &smA[b][ks][4096 + wbase]); gA1 += 32;
    };
    auto stageB = [&](int b, int ks) {
        gload_lds16(gB0, &smB[b][ks][wbase]);        gB0 += 32;
        gload_lds16(gB1, &smB[b][ks][4096 + wbase]); gB1 += 32;
    };

    // ---- fragment read offsets (16x16x32: row=lane&15, k=(lane>>4)*8) ----
    const int fr = lane & 15;
    const int hi = lane >> 4;       // k-block 0..3 within a 32-K subtile
    int aOff[8], bOff[4];
#pragma unroll
    for (int i = 0; i < 8; ++i) {
        const int r = waveM * 128 + i * 16 + fr;
        aOff[i] = r * 32 + (((hi + (r >> 1)) & 3) << 3);
    }
#pragma unroll
    for (int n = 0; n < 4; ++n) {
        const int r = waveN * 64 + n * 16 + fr;
        bOff[n] = r * 32 + (((hi + (r >> 1)) & 3) << 3);
    }

    f32x4 acc[8][4];
#pragma unroll
    for (int mi = 0; mi < 8; ++mi)
#pragma unroll
        for (int ni = 0; ni < 4; ++ni)
            acc[mi][ni] = (f32x4){0.f, 0.f, 0.f, 0.f};

    const int nk2 = K >> 6;         // K/64 K-tiles (64 or 224 here, >= 2)

    // ---- prologue: t0 full (8 regions) + t1 {A ks0, B ks0, B ks1} ----
    stageA(0, 0); stageB(0, 0);
    stageA(0, 1); stageB(0, 1);
    stageA(1, 0); stageB(1, 0);
    stageB(1, 1);
    asm volatile("s_waitcnt vmcnt(6)" ::: "memory");  // t0's 8 regions landed
    __builtin_amdgcn_s_barrier();

    for (int t = 0; t < nk2; ++t) {
        const int c = t & 1;
        f16x8 aF[4], bF0[4], bF1[4];

        // ---------- p0: A[c][0] mi0-3 + B[c][0]; stage A[c^1][1] (t+1)
#pragma unroll
        for (int i = 0; i < 4; ++i) aF[i]  = *(const f16x8*)(&smA[c][0][aOff[i]]);
#pragma unroll
        for (int n = 0; n < 4; ++n) bF0[n] = *(const f16x8*)(&smB[c][0][bOff[n]]);
        if (t + 1 < nk2) stageA(c ^ 1, 1);
        phase_pre();
#pragma unroll
        for (int i = 0; i < 4; ++i)
#pragma unroll
            for (int n = 0; n < 4; ++n)
                acc[i][n] = __builtin_amdgcn_mfma_f32_16x16x32_f16(
                    aF[i], bF0[n], acc[i][n], 0, 0, 0);
        phase_post();

        // ---------- p1: A[c][0] mi4-7; stage B[c][0] (t+2)
#pragma unroll
        for (int i = 0; i < 4; ++i) aF[i] = *(const f16x8*)(&smA[c][0][aOff[4 + i]]);
        if (t + 2 < nk2) stageB(c, 0);
        phase_pre();
#pragma unroll
        for (int i = 0; i < 4; ++i)
#pragma unroll
            for (int n = 0; n < 4; ++n)
                acc[4 + i][n] = __builtin_amdgcn_mfma_f32_16x16x32_f16(
                    aF[i], bF0[n], acc[4 + i][n], 0, 0, 0);
        phase_post();

        // ---------- p2: A[c][1] mi0-3 + B[c][1]; stage A[c][0] (t+2)
#pragma unroll
        for (int i = 0; i < 4; ++i) aF[i]  = *(const f16x8*)(&smA[c][1][aOff[i]]);
#pragma unroll
        for (int n = 0; n < 4; ++n) bF1[n] = *(const f16x8*)(&smB[c][1][bOff[n]]);
        if (t + 2 < nk2) stageA(c, 0);
        phase_pre();
#pragma unroll
        for (int i = 0; i < 4; ++i)
#pragma unroll
            for (int n = 0; n < 4; ++n)
                acc[i][n] = __builtin_amdgcn_mfma_f32_16x16x32_f16(
                    aF[i], bF1[n], acc[i][n], 0, 0, 0);
        phase_post();

        // ---------- p3: A[c][1] mi4-7; stage B[c][1] (t+2)
#pragma unroll
        for (int i = 0; i < 4; ++i) aF[i] = *(const f16x8*)(&smA[c][1][aOff[4 + i]]);
        if (t + 2 < nk2) stageB(c, 1);
        phase_pre();
#pragma unroll
        for (int i = 0; i < 4; ++i)
#pragma unroll
            for (int n = 0; n < 4; ++n)
                acc[4 + i][n] = __builtin_amdgcn_mfma_f32_16x16x32_f16(
                    aF[i], bF1[n], acc[4 + i][n], 0, 0, 0);
        __builtin_amdgcn_s_setprio(0);
        // counted vmcnt: tile t+1 fully landed; t's p1-p3 stages (6) in flight
        if (t + 2 < nk2) {
            asm volatile("s_waitcnt vmcnt(6)" ::: "memory");
        } else {
            asm volatile("s_waitcnt vmcnt(0)" ::: "memory");
        }
        __builtin_amdgcn_s_barrier();
    }

    // ---- epilogue: C/D layout col=lane&15, row=(lane>>4)*4+j ----
    const long long orBase = blockRow + waveM * 128 + hi * 4;
    if constexpr (EPI == 0) {
        const long long ocBase = blockCol + waveN * 64 + fr;
#pragma unroll
        for (int mi = 0; mi < 8; ++mi)
#pragma unroll
            for (int ni = 0; ni < 4; ++ni)
#pragma unroll
                for (int j = 0; j < 4; ++j) {
                    const long long idx =
                        (orBase + mi * 16 + j) * (long long)ldc +
                        (ocBase + ni * 16);
                    ((float*)Cv)[idx] = acc[mi][ni][j];
                }
    } else {
        // interleaved gate/up: ni even = gate, ni odd = up, same output col.
        const long long ocBase = (blockCol >> 1) + waveN * 32 + fr;
#pragma unroll
        for (int mi = 0; mi < 8; ++mi)
#pragma unroll
            for (int pi = 0; pi < 2; ++pi)
#pragma unroll
                for (int j = 0; j < 4; ++j) {
                    float g = acc[mi][2 * pi][j];
                    float u = acc[mi][2 * pi + 1][j];
                    float v = (g / (1.f + __expf(-g))) * u;   // silu(g)*u
                    const long long idx =
                        (orBase + mi * 16 + j) * (long long)ldc +
                        (ocBase + pi * 16);
                    ((f16*)Cv)[idx] = (f16)v;
                }
    }
}

// ======================= fallback path (f32 operands) ========================
template<bool IS16>
__device__ __forceinline__ f16x8 load8(const char* p) {
    if constexpr (IS16) return *(const f16x8*)p;
    const float* f = (const float*)p;
    return cvt8(*(const f32x4*)f, *(const f32x4*)(f + 4));
}

template<bool FUSED, bool A16, bool B16>
__global__ __launch_bounds__(256)
void mlp_gemm(const void* __restrict__ Av, const void* __restrict__ B0v,
              const void* __restrict__ B1v, void* __restrict__ Cv,
              int K, int ldc, int nRow, int nCol, int RG) {
    __shared__ __align__(16) f16 smA[128 * 32];
    __shared__ __align__(16) f16 smB0[128 * 32];
    __shared__ __align__(16) f16 smB1[FUSED ? 128 * 32 : 8];

    const int lin   = blockIdx.x;
    const int perSg = RG * nCol;
    const int sg    = lin / perSg;
    const int rem   = lin - sg * perSg;
    int rgIn = nRow - sg * RG; if (rgIn > RG) rgIn = RG;
    const int colB = rem / rgIn;
    const int rowB = sg * RG + (rem - colB * rgIn);

    const long long blockRow = (long long)rowB * 128;
    const long long blockCol = (long long)colB * 128;

    const int tid  = threadIdx.x;
    const int w    = tid >> 6;
    const int lane = tid & 63;
    const int waveM = w >> 1;
    const int waveN = w & 1;

    const int r0 = tid >> 2;
    const int s0 = tid & 3;
    const int szA = A16 ? 2 : 4;
    const int szB = B16 ? 2 : 4;
    const char* gA0  = (const char*)Av  + ((blockRow + r0)      * (long long)K + s0 * 8) * szA;
    const char* gA1  = (const char*)Av  + ((blockRow + r0 + 64) * (long long)K + s0 * 8) * szA;
    const char* gB00 = (const char*)B0v + ((blockCol + r0)      * (long long)K + s0 * 8) * szB;
    const char* gB01 = (const char*)B0v + ((blockCol + r0 + 64) * (long long)K + s0 * 8) * szB;
    const char* gB10 = FUSED ? (const char*)B1v + ((blockCol + r0)      * (long long)K + s0 * 8) * szB : nullptr;
    const char* gB11 = FUSED ? (const char*)B1v + ((blockCol + r0 + 64) * (long long)K + s0 * 8) * szB : nullptr;

    const int off0 = tid * 8;
    const int off1 = off0 + 2048;

    const int fr = lane & 15;
    const int fk = (lane >> 4) * 8;
    int offA[4], offB[4];
#pragma unroll
    for (int i = 0; i < 4; ++i) {
        offA[i] = (waveM * 64 + i * 16 + fr) * 32 + fk;
        offB[i] = (waveN * 64 + i * 16 + fr) * 32 + fk;
    }

    f32x4 acc0[4][4];
    f32x4 acc1[4][4];
#pragma unroll
    for (int mi = 0; mi < 4; ++mi)
#pragma unroll
        for (int ni = 0; ni < 4; ++ni) {
            acc0[mi][ni] = (f32x4){0.f, 0.f, 0.f, 0.f};
            if constexpr (FUSED) acc1[mi][ni] = (f32x4){0.f, 0.f, 0.f, 0.f};
        }

    const int ksteps = K >> 5;
    for (int kt = 0; kt < ksteps; ++kt) {
        f16x8 vA0  = load8<A16>(gA0);
        f16x8 vA1  = load8<A16>(gA1);
        f16x8 vB00 = load8<B16>(gB00);
        f16x8 vB01 = load8<B16>(gB01);
        f16x8 vB10, vB11;
        if constexpr (FUSED) {
            vB10 = load8<B16>(gB10);
            vB11 = load8<B16>(gB11);
        }
        gA0 += 32 * szA; gA1 += 32 * szA;
        gB00 += 32 * szB; gB01 += 32 * szB;
        if constexpr (FUSED) { gB10 += 32 * szB; gB11 += 32 * szB; }

        __syncthreads();

        *(f16x8*)(smA  + off0) = vA0;
        *(f16x8*)(smA  + off1) = vA1;
        *(f16x8*)(smB0 + off0) = vB00;
        *(f16x8*)(smB0 + off1) = vB01;
        if constexpr (FUSED) {
            *(f16x8*)(smB1 + off0) = vB10;
            *(f16x8*)(smB1 + off1) = vB11;
        }

        __syncthreads();

        f16x8 aF[4], bF[4], b1F[4];
#pragma unroll
        for (int i = 0; i < 4; ++i) aF[i] = *(const f16x8*)(smA + offA[i]);
#pragma unroll
        for (int i = 0; i < 4; ++i) bF[i] = *(const f16x8*)(smB0 + offB[i]);
        if constexpr (FUSED) {
#pragma unroll
            for (int i = 0; i < 4; ++i) b1F[i] = *(const f16x8*)(smB1 + offB[i]);
        }

#pragma unroll
        for (int mi = 0; mi < 4; ++mi)
#pragma unroll
            for (int ni = 0; ni < 4; ++ni) {
                acc0[mi][ni] = __builtin_amdgcn_mfma_f32_16x16x32_f16(
                    aF[mi], bF[ni], acc0[mi][ni], 0, 0, 0);
                if constexpr (FUSED)
                    acc1[mi][ni] = __builtin_amdgcn_mfma_f32_16x16x32_f16(
                        aF[mi], b1F[ni], acc1[mi][ni], 0, 0, 0);
            }
    }

    const long long orBase = blockRow + waveM * 64 + ((lane >> 4) * 4);
    const long long ocBase = blockCol + waveN * 64 + fr;
#pragma unroll
    for (int mi = 0; mi < 4; ++mi)
#pragma unroll
        for (int ni = 0; ni < 4; ++ni)
#pragma unroll
            for (int j = 0; j < 4; ++j) {
                const long long idx =
                    (orBase + mi * 16 + j) * (long long)ldc + (ocBase + ni * 16);
                if constexpr (FUSED) {
                    float gv = acc0[mi][ni][j];
                    float uv = acc1[mi][ni][j];
                    float v = (gv / (1.f + __expf(-gv))) * uv;
                    ((f16*)Cv)[idx] = (f16)v;
                } else {
                    ((float*)Cv)[idx] = acc0[mi][ni][j];
                }
            }
}

extern "C" void kernel_launch(void* const* d_in, const int* in_sizes, int n_in,
                              void* d_out, int out_size, void* d_ws, size_t ws_size,
                              hipStream_t stream) {
    const float* x  = (const float*)d_in[0];   // [T, HD] f32 (fp16-exact)
    const float* Wg = (const float*)d_in[1];   // [M, HD] f32
    const float* Wu = (const float*)d_in[2];   // [M, HD] f32
    const float* Wd = (const float*)d_in[3];   // [HD, M] f32
    float* out = (float*)d_out;                // [T, HD] f32

    const int HD = 4096;
    const int T  = in_sizes[0] / HD;           // 8192
    const int M  = in_sizes[1] / HD;           // 14336

    const long long nW = (long long)M * HD;
    const long long nX = (long long)T * HD;
    const size_t wBytes = (size_t)nW * 2;      // 117.4 MB
    const size_t xBytes = (size_t)nX * 2;      // 67.1 MB
    const size_t hRow   = (size_t)M * 2;
    const size_t minH   = 256 * hRow;          // 7.34 MB (one 256-row chunk)

    // carve d_ws: [Wgu (2x interleaved)][Wd16][X16][H...]
    char* p = (char*)d_ws;
    size_t rem = ws_size;
    f16 *Wgu = nullptr, *Wd16 = nullptr, *X16 = nullptr;
    bool fast = false;
    if (rem >= 3 * wBytes + xBytes + minH) {
        Wgu  = (f16*)p; p += 2 * wBytes;
        Wd16 = (f16*)p; p += wBytes;
        X16  = (f16*)p; p += xBytes;
        rem -= 3 * wBytes + xBytes;
        fast = true;
    }
    f16* H = (f16*)p;

    if (fast) {
        long long maxRows = (long long)(rem / hRow);
        int chunk = (int)((maxRows / 256) * 256);
        if (chunk > T) chunk = T;

        cvt_interleave_f32_f16<<<2048, 256, 0, stream>>>(Wg, Wu, Wgu, 2 * nW);
        cvt_f32_f16<<<2048, 256, 0, stream>>>(Wd, Wd16, nW);
        cvt_f32_f16<<<2048, 256, 0, stream>>>(x, X16, nX);

        const int nColGU = (2 * M) / 256;   // 112
        const int nColD  = HD / 256;        // 16
        for (int t0 = 0; t0 < T; t0 += chunk) {
            int rows = (T - t0 < chunk) ? (T - t0) : chunk;
            int nRow = rows / 256;
            // GEMM1: x @ Wgu^T (interleaved) -> H = silu(gate)*up  [rows, M]
            mlp_gemm8p<3><<<dim3(nRow * nColGU), 512, 0, stream>>>(
                X16 + (size_t)t0 * HD, Wgu, H, HD, M, nRow, nColGU, nRow);
            // GEMM2: H @ Wd^T -> out [rows, HD] f32
            int RG = (nRow < 16) ? nRow : 16;
            mlp_gemm8p<0><<<dim3(nRow * nColD), 512, 0, stream>>>(
                H, Wd16, out + (size_t)t0 * HD, M, HD, nRow, nColD, RG);
        }
        return;
    }

    // ---------- fallback: f32 operands, reg-staged 128-tiles ----------
    long long maxRows = (long long)(ws_size / hRow);
    int chunk = (int)((maxRows / 128) * 128);
    if (chunk > T) chunk = T;
    if (chunk <= 0) {
        fill_sentinel_f32<<<1024, 256, 0, stream>>>(out, (long long)out_size);
        return;
    }
    f16* Hf = (f16*)d_ws;
    for (int t0 = 0; t0 < T; t0 += chunk) {
        int rows = (T - t0 < chunk) ? (T - t0) : chunk;
        int nRow = rows / 128;
        {
            int nCol = M / 128;
            mlp_gemm<true, false, false><<<dim3(nRow * nCol), 256, 0, stream>>>(
                x + (size_t)t0 * HD, Wg, Wu, Hf, HD, M, nRow, nCol, nRow);
        }
        {
            int nCol = HD / 128;
            int RG = (nRow < 32) ? nRow : 32;
            mlp_gemm<false, true, false><<<dim3(nRow * nCol), 256, 0, stream>>>(
                Hf, Wd, nullptr, out + (size_t)t0 * HD, M, HD, nRow, nCol, RG);
        }
    }
}

// Round 25
// 2759.225 us; speedup vs baseline: 1.0171x; 1.0171x over previous
//
#include <hip/hip_runtime.h>

typedef _Float16 f16;
typedef _Float16 f16x8 __attribute__((ext_vector_type(8)));
typedef float f32x4 __attribute__((ext_vector_type(4)));

__device__ __forceinline__ f16x8 cvt8(f32x4 lo, f32x4 hi) {
    f16x8 h;
    h[0] = (f16)lo[0]; h[1] = (f16)lo[1]; h[2] = (f16)lo[2]; h[3] = (f16)lo[3];
    h[4] = (f16)hi[0]; h[5] = (f16)hi[1]; h[6] = (f16)hi[2]; h[7] = (f16)hi[3];
    return h;
}

__global__ __launch_bounds__(256)
void cvt_f32_f16(const float* __restrict__ in, f16* __restrict__ out, long long n) {
    long long i = ((long long)blockIdx.x * 256 + threadIdx.x) * 8;
    const long long stride = (long long)gridDim.x * 256 * 8;
    for (; i < n; i += stride) {
        f32x4 a = *(const f32x4*)(in + i);
        f32x4 b = *(const f32x4*)(in + i + 4);
        *(f16x8*)(out + i) = cvt8(a, b);
    }
}

// Interleave Wg/Wu rows 16-wise into Wgu [2M, HD] f16 (r22, verified):
//   Wgu row R: (R&31)<16 -> Wg row (R>>5)*16+(R&15); else Wu same.
// Makes the fused GEMM1 a SINGLE-B GEMM structurally identical to the
// down-GEMM; silu(g)*u stays in-register in the epilogue.
__global__ __launch_bounds__(256)
void cvt_interleave_f32_f16(const float* __restrict__ Wg,
                            const float* __restrict__ Wu,
                            f16* __restrict__ out, long long total) {
    long long i = ((long long)blockIdx.x * 256 + threadIdx.x) * 8;
    const long long stride = (long long)gridDim.x * 256 * 8;
    for (; i < total; i += stride) {
        const long long row = i >> 12;           // HD = 4096
        const int col = (int)(i & 4095);
        const long long srow = ((row >> 5) << 4) | (row & 15);
        const float* src = ((row & 16) ? Wu : Wg) + srow * 4096 + col;
        *(f16x8*)(out + i) = cvt8(*(const f32x4*)src, *(const f32x4*)(src + 4));
    }
}

__global__ void fill_sentinel_f32(float* __restrict__ out, long long n) {
    long long i = (long long)blockIdx.x * blockDim.x + threadIdx.x;
    long long stride = (long long)gridDim.x * blockDim.x;
    for (; i < n; i += stride) out[i] = 1.0f;
}

// Async global->LDS, 16B/lane. Pass the WAVE-UNIFORM LDS base; HW adds lane*16.
__device__ __forceinline__ void gload_lds16(const f16* g, f16* l) {
    __builtin_amdgcn_global_load_lds(
        (const __attribute__((address_space(1))) unsigned int*)(unsigned long long)g,
        (__attribute__((address_space(3))) unsigned int*)(unsigned int)(unsigned long long)l,
        16, 0, 0);
}

// ============================== fast path (all-f16) ==========================
// FINAL CHAMPION (r22, 2755.8us measured): single-B NT GEMM.
//   BM=256, BN=256, BK=32, 512 thr (8 waves 2Mx4N), wave 128x64, acc=128 VGPR.
//   3 LDS bufs (96 KB), depth-2 counted vmcnt(4): prologue stage(0),stage(1);
//   iter t: vmcnt(4) [stage(t) done, stage(t+1) in flight], s_barrier,
//   stage(t+2)->buf[(t+2)%3], compute(t). VMEM never drains mid-loop.
//   Rotation swizzle (0 conflicts measured): LDS[r][blk] holds global 16B
//   blk (blk - r/2)&3; frag read of k-blk hi at row r -> (hi + r/2)&3.
//   MFMA 16x16x32 f16; C/D col=lane&15, row=(lane>>4)*4+j (verified).
// EPI=0 (down): C = f32 out [rows, HD].
// EPI=3 (gate+up, INTERLEAVED B = Wgu): B-fragment ni even/odd = gate/up for
//   the SAME output cols -> epilogue silu(g)*u in-register -> f16 H at col
//   blockCol/2 + waveN*32 + (ni>>1)*16 + fr.
// Session plateau note (r8-r24, 12 counter-verified variants): ~54% MfmaUtil
//   is this structure's issue-serialization floor; phase-split schedules
//   (r12/r13/r24), 32x32 MFMA (r14/r15), de-fusion (r17), cache remaps
//   (r18/r19) all measured neutral-to-worse.
template<int EPI>
__global__ __launch_bounds__(512, 2)
void mlp_gemm16d(const f16* __restrict__ A, const f16* __restrict__ B0,
                 void* __restrict__ Cv, int K, int ldc,
                 int nRow, int nCol, int RG) {
    __shared__ __align__(16) f16 smA[3][256 * 32];
    __shared__ __align__(16) f16 smB0[3][256 * 32];

    // ---- block remap: supergroups of RG row-blocks, col-outer within ----
    const int lin   = blockIdx.x;
    const int perSg = RG * nCol;
    const int sg    = lin / perSg;
    const int rem   = lin - sg * perSg;
    int rgIn = nRow - sg * RG; if (rgIn > RG) rgIn = RG;
    const int colB = rem / rgIn;
    const int rowB = sg * RG + (rem - colB * rgIn);

    const long long blockRow = (long long)rowB * 256;
    const long long blockCol = (long long)colB * 256;

    const int tid  = threadIdx.x;
    const int w    = tid >> 6;      // 0..7
    const int lane = tid & 63;
    const int waveM = w >> 2;       // 0..1 -> 128 rows
    const int waveN = w & 3;        // 0..3 -> 64 B-rows

    // ---- staging: thread covers 16B chunk (dr=tid>>2, blk=tid&3);
    // pre-rotated global source block gblk = (blk - dr/2)&3 (m173 pattern);
    // +128-row issues keep gblk (128/2 == 0 mod 4).
    const int dr   = tid >> 2;
    const int dblk = tid & 3;
    const int gblk = (dblk - (dr >> 1)) & 3;
    const f16* gA0  = A  + (blockRow + dr) * (long long)K + gblk * 8;  // rows 0-127
    const f16* gA1  = gA0 + 128 * (long long)K;                        // rows 128-255
    const f16* gB0a = B0 + (blockCol + dr) * (long long)K + gblk * 8;
    const f16* gB0b = gB0a + 128 * (long long)K;
    const int wbase = w * 512;      // wave-uniform LDS base (elems)

    // ---- fragment read offsets (16x16x32: row=lane&15, k=(lane>>4)*8) ----
    const int fr = lane & 15;
    const int hi = lane >> 4;       // k-block 0..3
    int aOff[8], bOff[4];
#pragma unroll
    for (int i = 0; i < 8; ++i) {
        const int r = waveM * 128 + i * 16 + fr;
        aOff[i] = r * 32 + (((hi + (r >> 1)) & 3) << 3);
    }
#pragma unroll
    for (int n = 0; n < 4; ++n) {
        const int r = waveN * 64 + n * 16 + fr;
        bOff[n] = r * 32 + (((hi + (r >> 1)) & 3) << 3);
    }

    f32x4 acc0[8][4];
#pragma unroll
    for (int mi = 0; mi < 8; ++mi)
#pragma unroll
        for (int ni = 0; ni < 4; ++ni)
            acc0[mi][ni] = (f32x4){0.f, 0.f, 0.f, 0.f};

    auto stage = [&](int b) {   // exactly 4 VMEM instructions per call
        gload_lds16(gA0,  &smA[b][wbase]);           gA0  += 32;
        gload_lds16(gA1,  &smA[b][4096 + wbase]);    gA1  += 32;
        gload_lds16(gB0a, &smB0[b][wbase]);          gB0a += 32;
        gload_lds16(gB0b, &smB0[b][4096 + wbase]);   gB0b += 32;
    };

    auto compute = [&](int b) {
        f16x8 aF[8], bF[4];
#pragma unroll
        for (int i = 0; i < 8; ++i) aF[i] = *(const f16x8*)(&smA[b][aOff[i]]);
#pragma unroll
        for (int n = 0; n < 4; ++n) bF[n] = *(const f16x8*)(&smB0[b][bOff[n]]);
#pragma unroll
        for (int mi = 0; mi < 8; ++mi)
#pragma unroll
            for (int ni = 0; ni < 4; ++ni)
                acc0[mi][ni] = __builtin_amdgcn_mfma_f32_16x16x32_f16(
                    aF[mi], bF[ni], acc0[mi][ni], 0, 0, 0);
    };

    const int nk = K >> 5;          // K/32 steps (>= 2)
    stage(0);
    stage(1);
    int cur = 0;
    for (int t = 0; t < nk - 1; ++t) {
        // retire stage(t) (8 outstanding -> 4); stage(t+1) stays in flight
        asm volatile("s_waitcnt vmcnt(4)" ::: "memory");
        __builtin_amdgcn_s_barrier();       // stage(t) visible; prev reads done
        __builtin_amdgcn_sched_barrier(0);
        if (t + 2 < nk) {
            int nb = cur + 2; if (nb >= 3) nb -= 3;
            stage(nb);                      // covered by ~2 compute phases
        }
        compute(cur);
        cur = (cur == 2) ? 0 : cur + 1;
    }
    asm volatile("s_waitcnt vmcnt(0)" ::: "memory");
    __builtin_amdgcn_s_barrier();
    __builtin_amdgcn_sched_barrier(0);
    compute(cur);

    // ---- epilogue: C/D layout col=lane&15, row=(lane>>4)*4+j ----
    const long long orBase = blockRow + waveM * 128 + hi * 4;
    if constexpr (EPI == 0) {
        const long long ocBase = blockCol + waveN * 64 + fr;
#pragma unroll
        for (int mi = 0; mi < 8; ++mi)
#pragma unroll
            for (int ni = 0; ni < 4; ++ni)
#pragma unroll
                for (int j = 0; j < 4; ++j) {
                    const long long idx =
                        (orBase + mi * 16 + j) * (long long)ldc +
                        (ocBase + ni * 16);
                    ((float*)Cv)[idx] = acc0[mi][ni][j];
                }
    } else {
        // interleaved gate/up: ni even = gate, ni odd = up, same output col.
        // H col = blockCol/2 + waveN*32 + (ni>>1)*16 + fr.
        const long long ocBase = (blockCol >> 1) + waveN * 32 + fr;
#pragma unroll
        for (int mi = 0; mi < 8; ++mi)
#pragma unroll
            for (int pi = 0; pi < 2; ++pi)
#pragma unroll
                for (int j = 0; j < 4; ++j) {
                    float g = acc0[mi][2 * pi][j];
                    float u = acc0[mi][2 * pi + 1][j];
                    float v = (g / (1.f + __expf(-g))) * u;   // silu(g)*u
                    const long long idx =
                        (orBase + mi * 16 + j) * (long long)ldc +
                        (ocBase + pi * 16);
                    ((f16*)Cv)[idx] = (f16)v;
                }
    }
}

// ======================= fallback path (f32 operands) ========================
template<bool IS16>
__device__ __forceinline__ f16x8 load8(const char* p) {
    if constexpr (IS16) return *(const f16x8*)p;
    const float* f = (const float*)p;
    return cvt8(*(const f32x4*)f, *(const f32x4*)(f + 4));
}

template<bool FUSED, bool A16, bool B16>
__global__ __launch_bounds__(256)
void mlp_gemm(const void* __restrict__ Av, const void* __restrict__ B0v,
              const void* __restrict__ B1v, void* __restrict__ Cv,
              int K, int ldc, int nRow, int nCol, int RG) {
    __shared__ __align__(16) f16 smA[128 * 32];
    __shared__ __align__(16) f16 smB0[128 * 32];
    __shared__ __align__(16) f16 smB1[FUSED ? 128 * 32 : 8];

    const int lin   = blockIdx.x;
    const int perSg = RG * nCol;
    const int sg    = lin / perSg;
    const int rem   = lin - sg * perSg;
    int rgIn = nRow - sg * RG; if (rgIn > RG) rgIn = RG;
    const int colB = rem / rgIn;
    const int rowB = sg * RG + (rem - colB * rgIn);

    const long long blockRow = (long long)rowB * 128;
    const long long blockCol = (long long)colB * 128;

    const int tid  = threadIdx.x;
    const int w    = tid >> 6;
    const int lane = tid & 63;
    const int waveM = w >> 1;
    const int waveN = w & 1;

    const int r0 = tid >> 2;
    const int s0 = tid & 3;
    const int szA = A16 ? 2 : 4;
    const int szB = B16 ? 2 : 4;
    const char* gA0  = (const char*)Av  + ((blockRow + r0)      * (long long)K + s0 * 8) * szA;
    const char* gA1  = (const char*)Av  + ((blockRow + r0 + 64) * (long long)K + s0 * 8) * szA;
    const char* gB00 = (const char*)B0v + ((blockCol + r0)      * (long long)K + s0 * 8) * szB;
    const char* gB01 = (const char*)B0v + ((blockCol + r0 + 64) * (long long)K + s0 * 8) * szB;
    const char* gB10 = FUSED ? (const char*)B1v + ((blockCol + r0)      * (long long)K + s0 * 8) * szB : nullptr;
    const char* gB11 = FUSED ? (const char*)B1v + ((blockCol + r0 + 64) * (long long)K + s0 * 8) * szB : nullptr;

    const int off0 = tid * 8;
    const int off1 = off0 + 2048;

    const int fr = lane & 15;
    const int fk = (lane >> 4) * 8;
    int offA[4], offB[4];
#pragma unroll
    for (int i = 0; i < 4; ++i) {
        offA[i] = (waveM * 64 + i * 16 + fr) * 32 + fk;
        offB[i] = (waveN * 64 + i * 16 + fr) * 32 + fk;
    }

    f32x4 acc0[4][4];
    f32x4 acc1[4][4];
#pragma unroll
    for (int mi = 0; mi < 4; ++mi)
#pragma unroll
        for (int ni = 0; ni < 4; ++ni) {
            acc0[mi][ni] = (f32x4){0.f, 0.f, 0.f, 0.f};
            if constexpr (FUSED) acc1[mi][ni] = (f32x4){0.f, 0.f, 0.f, 0.f};
        }

    const int ksteps = K >> 5;
    for (int kt = 0; kt < ksteps; ++kt) {
        f16x8 vA0  = load8<A16>(gA0);
        f16x8 vA1  = load8<A16>(gA1);
        f16x8 vB00 = load8<B16>(gB00);
        f16x8 vB01 = load8<B16>(gB01);
        f16x8 vB10, vB11;
        if constexpr (FUSED) {
            vB10 = load8<B16>(gB10);
            vB11 = load8<B16>(gB11);
        }
        gA0 += 32 * szA; gA1 += 32 * szA;
        gB00 += 32 * szB; gB01 += 32 * szB;
        if constexpr (FUSED) { gB10 += 32 * szB; gB11 += 32 * szB; }

        __syncthreads();

        *(f16x8*)(smA  + off0) = vA0;
        *(f16x8*)(smA  + off1) = vA1;
        *(f16x8*)(smB0 + off0) = vB00;
        *(f16x8*)(smB0 + off1) = vB01;
        if constexpr (FUSED) {
            *(f16x8*)(smB1 + off0) = vB10;
            *(f16x8*)(smB1 + off1) = vB11;
        }

        __syncthreads();

        f16x8 aF[4], bF[4], b1F[4];
#pragma unroll
        for (int i = 0; i < 4; ++i) aF[i] = *(const f16x8*)(smA + offA[i]);
#pragma unroll
        for (int i = 0; i < 4; ++i) bF[i] = *(const f16x8*)(smB0 + offB[i]);
        if constexpr (FUSED) {
#pragma unroll
            for (int i = 0; i < 4; ++i) b1F[i] = *(const f16x8*)(smB1 + offB[i]);
        }

#pragma unroll
        for (int mi = 0; mi < 4; ++mi)
#pragma unroll
            for (int ni = 0; ni < 4; ++ni) {
                acc0[mi][ni] = __builtin_amdgcn_mfma_f32_16x16x32_f16(
                    aF[mi], bF[ni], acc0[mi][ni], 0, 0, 0);
                if constexpr (FUSED)
                    acc1[mi][ni] = __builtin_amdgcn_mfma_f32_16x16x32_f16(
                        aF[mi], b1F[ni], acc1[mi][ni], 0, 0, 0);
            }
    }

    const long long orBase = blockRow + waveM * 64 + ((lane >> 4) * 4);
    const long long ocBase = blockCol + waveN * 64 + fr;
#pragma unroll
    for (int mi = 0; mi < 4; ++mi)
#pragma unroll
        for (int ni = 0; ni < 4; ++ni)
#pragma unroll
            for (int j = 0; j < 4; ++j) {
                const long long idx =
                    (orBase + mi * 16 + j) * (long long)ldc + (ocBase + ni * 16);
                if constexpr (FUSED) {
                    float gv = acc0[mi][ni][j];
                    float uv = acc1[mi][ni][j];
                    float v = (gv / (1.f + __expf(-gv))) * uv;
                    ((f16*)Cv)[idx] = (f16)v;
                } else {
                    ((float*)Cv)[idx] = acc0[mi][ni][j];
                }
            }
}

extern "C" void kernel_launch(void* const* d_in, const int* in_sizes, int n_in,
                              void* d_out, int out_size, void* d_ws, size_t ws_size,
                              hipStream_t stream) {
    const float* x  = (const float*)d_in[0];   // [T, HD] f32 (fp16-exact)
    const float* Wg = (const float*)d_in[1];   // [M, HD] f32
    const float* Wu = (const float*)d_in[2];   // [M, HD] f32
    const float* Wd = (const float*)d_in[3];   // [HD, M] f32
    float* out = (float*)d_out;                // [T, HD] f32

    const int HD = 4096;
    const int T  = in_sizes[0] / HD;           // 8192
    const int M  = in_sizes[1] / HD;           // 14336

    const long long nW = (long long)M * HD;
    const long long nX = (long long)T * HD;
    const size_t wBytes = (size_t)nW * 2;      // 117.4 MB
    const size_t xBytes = (size_t)nX * 2;      // 67.1 MB
    const size_t hRow   = (size_t)M * 2;
    const size_t minH   = 256 * hRow;          // 7.34 MB (one 256-row chunk)

    // carve d_ws: [Wgu (2x interleaved)][Wd16][X16][H...]
    char* p = (char*)d_ws;
    size_t rem = ws_size;
    f16 *Wgu = nullptr, *Wd16 = nullptr, *X16 = nullptr;
    bool fast = false;
    if (rem >= 3 * wBytes + xBytes + minH) {
        Wgu  = (f16*)p; p += 2 * wBytes;
        Wd16 = (f16*)p; p += wBytes;
        X16  = (f16*)p; p += xBytes;
        rem -= 3 * wBytes + xBytes;
        fast = true;
    }
    f16* H = (f16*)p;

    if (fast) {
        long long maxRows = (long long)(rem / hRow);
        int chunk = (int)((maxRows / 256) * 256);
        if (chunk > T) chunk = T;

        cvt_interleave_f32_f16<<<2048, 256, 0, stream>>>(Wg, Wu, Wgu, 2 * nW);
        cvt_f32_f16<<<2048, 256, 0, stream>>>(Wd, Wd16, nW);
        cvt_f32_f16<<<2048, 256, 0, stream>>>(x, X16, nX);

        const int nColGU = (2 * M) / 256;   // 112
        const int nColD  = HD / 256;        // 16
        for (int t0 = 0; t0 < T; t0 += chunk) {
            int rows = (T - t0 < chunk) ? (T - t0) : chunk;
            int nRow = rows / 256;
            // GEMM1: x @ Wgu^T (interleaved) -> H = silu(gate)*up  [rows, M]
            mlp_gemm16d<3><<<dim3(nRow * nColGU), 512, 0, stream>>>(
                X16 + (size_t)t0 * HD, Wgu, H, HD, M, nRow, nColGU, nRow);
            // GEMM2: H @ Wd^T -> out [rows, HD] f32
            int RG = (nRow < 16) ? nRow : 16;
            mlp_gemm16d<0><<<dim3(nRow * nColD), 512, 0, stream>>>(
                H, Wd16, out + (size_t)t0 * HD, M, HD, nRow, nColD, RG);
        }
        return;
    }

    // ---------- fallback: f32 operands, reg-staged 128-tiles ----------
    long long maxRows = (long long)(ws_size / hRow);
    int chunk = (int)((maxRows / 128) * 128);
    if (chunk > T) chunk = T;
    if (chunk <= 0) {
        fill_sentinel_f32<<<1024, 256, 0, stream>>>(out, (long long)out_size);
        return;
    }
    f16* Hf = (f16*)d_ws;
    for (int t0 = 0; t0 < T; t0 += chunk) {
        int rows = (T - t0 < chunk) ? (T - t0) : chunk;
        int nRow = rows / 128;
        {
            int nCol = M / 128;
            mlp_gemm<true, false, false><<<dim3(nRow * nCol), 256, 0, stream>>>(
                x + (size_t)t0 * HD, Wg, Wu, Hf, HD, M, nRow, nCol, nRow);
        }
        {
            int nCol = HD / 128;
            int RG = (nRow < 32) ? nRow : 32;
            mlp_gemm<false, true, false><<<dim3(nRow * nCol), 256, 0, stream>>>(
                Hf, Wd, nullptr, out + (size_t)t0 * HD, M, HD, nRow, nCol, RG);
        }
    }
}